// Round 12
// baseline (212.246 us; speedup 1.0000x reference)
//
#include <hip/hip_runtime.h>
#include <math.h>

// Match numpy/XLA fp32 semantics: no compiler-introduced FMA contraction.
#pragma clang fp contract(off)

#define KCAP 64       // output neighbor cap (reference K)
#define GMAX 54       // max grid resolution per dim
#define XMIN -8.0f
#define SPAN 16.0f

// Same grid derivation as the passing round-5/11 kernels. cell >= 2r ensures
// any true neighbor lies in the +-1 bin neighborhood even under fp rounding.
__device__ __forceinline__ void grid_params(const float* __restrict__ radius_p,
                                            float* rr, float* cell, int* G) {
  float r = radius_p[0];
  *rr = r * r;
  float c = fmaxf(2.0f * r, SPAN / (float)GMAX);
  int g = (int)ceilf(SPAN / c);
  *G = g < 1 ? 1 : (g > GMAX ? GMAX : g);
  *cell = c;
}

__device__ __forceinline__ int bin1(float v, float cell, int G) {
  int b = (int)floorf((v - XMIN) / cell);
  return b < 0 ? 0 : (b > G - 1 ? G - 1 : b);
}

// Dispatch 1: 2D (y,z) counting sort, one block per z-row, fixed per-row
// capacity N (region base z*N). 4 sub-histograms (wave&3) cut LDS-atomic
// same-address chains 4x; pass A and pass B use the same thread->point
// mapping so per-slot capacities are exact. Within-cell order is arbitrary
// (grouped by sub-histogram) — final output is sorted, so irrelevant.
__global__ __launch_bounds__(1024) void build_kernel(
    const float* __restrict__ pts, const float* __restrict__ radius_p,
    float4* __restrict__ sortedPts, int* __restrict__ sortedIdx,
    int* __restrict__ rowStart, int* __restrict__ rowEnd,
    int* __restrict__ done, int N) {
  __shared__ int cnt[4][GMAX];
  __shared__ int cur[4][GMAX];
  float rr, cell; int G;
  grid_params(radius_p, &rr, &cell, &G);
  const int z = blockIdx.x;
  if (z == 0 && threadIdx.x == 0) *done = 0;  // reset last-block ticket
  if (z >= G) return;
  const int sh = (threadIdx.x >> 6) & 3;  // sub-histogram id

  for (int i = threadIdx.x; i < 4 * GMAX; i += 1024) (&cnt[0][0])[i] = 0;
  __syncthreads();

  // Pass A: count this z-row's points per (sub-histogram, y-bin).
  for (int i = threadIdx.x; i < N; i += 1024) {
    float yv = pts[3 * i + 1], zv = pts[3 * i + 2];
    if (bin1(zv, cell, G) == z) atomicAdd(&cnt[sh][bin1(yv, cell, G)], 1);
  }
  __syncthreads();

  // Wave 0: scan <=54 y-bins; publish row ranges + per-sub-histogram cursors.
  if (threadIdx.x < 64) {
    int lane = threadIdx.x;
    int c0 = 0, c1 = 0, c2 = 0, c3 = 0, c = 0;
    if (lane < G) {
      c0 = cnt[0][lane]; c1 = cnt[1][lane];
      c2 = cnt[2][lane]; c3 = cnt[3][lane];
      c = c0 + c1 + c2 + c3;
    }
    int pre = c;
    for (int off = 1; off < 64; off <<= 1) {
      int v = __shfl_up(pre, off);
      if (lane >= off) pre += v;
    }
    if (lane < G) {
      int s0 = pre - c;  // exclusive prefix within this z-row
      rowStart[z * G + lane] = z * N + s0;
      rowEnd[z * G + lane] = z * N + pre;
      cur[0][lane] = s0;
      cur[1][lane] = s0 + c0;
      cur[2][lane] = s0 + c0 + c1;
      cur[3][lane] = s0 + c0 + c1 + c2;
    }
  }
  __syncthreads();

  // Pass B: scatter into cell-ordered storage as (x,y,z,p2).
  for (int i = threadIdx.x; i < N; i += 1024) {
    float xv = pts[3 * i], yv = pts[3 * i + 1], zv = pts[3 * i + 2];
    if (bin1(zv, cell, G) == z) {
      int pos = atomicAdd(&cur[sh][bin1(yv, cell, G)], 1);
      float p2 = (xv * xv + yv * yv) + zv * zv;  // numpy sum order, no fma
      sortedPts[z * N + pos] = make_float4(xv, yv, zv, p2);
      sortedIdx[z * N + pos] = i;
    }
  }
}

// Dispatch 2: ONE BLOCK (4 waves) PER QUERY. Each wave scans every-4th
// 64-chunk of the 3 contiguous candidate ranges (4x shorter serial load
// chains, 4x more waves -> latency hidden, tail rebalanced). Per-wave
// partials ballot-compacted into LDS; wave 0 concatenates and runs the
// 64-lane bitonic sort by (d2, idx) (= jax.lax.top_k tie-break). The LAST
// block (device-scope atomic ticket + threadfence) runs the row-splits scan.
__global__ __launch_bounds__(256) void query_kernel(
    const float* __restrict__ queries, const float* __restrict__ radius_p,
    const float4* __restrict__ sortedPts, const int* __restrict__ sortedIdx,
    const int* __restrict__ rowStart, const int* __restrict__ rowEnd,
    float* __restrict__ out_idx, float* __restrict__ out_dist,
    float* __restrict__ out_rs, int* __restrict__ qcounts,
    int* __restrict__ done, int N, int M) {
  __shared__ float d2p[4][KCAP];
  __shared__ int idxp[4][KCAP];
  __shared__ int pcnt[4];
  __shared__ int wsum[4];
  __shared__ int amLastS;
  const int lane = threadIdx.x & 63;
  const int wv = threadIdx.x >> 6;
  const int q = blockIdx.x;
  float rr, cell; int G;
  grid_params(radius_p, &rr, &cell, &G);

  if (q < M) {
    float qx = queries[3 * q], qy = queries[3 * q + 1], qz = queries[3 * q + 2];
    float q2 = (qx * qx + qy * qy) + qz * qz;  // numpy sum order, no fma
    int cy = bin1(qy, cell, G), cz = bin1(qz, cell, G);
    int ylo = max(cy - 1, 0), yhi = min(cy + 1, G - 1);
    // Gather up to 3 contiguous ranges upfront (independent loads).
    int rs_[3], re_[3];
    int nr = 0;
    for (int dz = -1; dz <= 1; ++dz) {
      int zz = cz + dz;
      if (zz < 0 || zz >= G) continue;
      rs_[nr] = rowStart[zz * G + ylo];
      re_[nr] = rowEnd[zz * G + yhi];
      ++nr;
    }
    int cnt = 0;  // this wave's partial hit count
    for (int t = 0; t < nr; ++t) {
      const int e = re_[t];
      for (int b = rs_[t] + wv * 64; b < e; b += 256) {
        int i = b + lane;
        bool valid = i < e;
        float4 p = valid ? sortedPts[i] : make_float4(0.f, 0.f, 0.f, INFINITY);
        // Bit-identical per-pair arithmetic (all passing rounds):
        float dot = fmaf(p.z, qz, fmaf(p.y, qy, p.x * qx));
        float sdd = q2 + p.w;
        float d2 = fmaf(dot, -2.0f, sdd);   // == sdd - 2*dot exactly
        bool hit = valid && (d2 <= rr);     // unclamped == clamped membership
        unsigned long long mask = __ballot(hit);
        int pos = cnt + __popcll(mask & ((1ull << lane) - 1ull));
        if (hit && pos < KCAP) {
          d2p[wv][pos] = fmaxf(d2, 0.0f);   // clamp on store
          idxp[wv][pos] = sortedIdx[i];
        }
        cnt += __popcll(mask);
      }
    }
    if (lane == 0) pcnt[wv] = cnt < KCAP ? cnt : KCAP;
  }
  __syncthreads();

  if (q < M && wv == 0) {
    int c0 = pcnt[0], c1 = pcnt[1], c2 = pcnt[2], c3 = pcnt[3];
    int o1 = c0, o2 = c0 + c1, o3 = c0 + c1 + c2;
    int total = o3 + c3;
    int tot64 = total < KCAP ? total : KCAP;
    float d2 = INFINITY;
    int idx = 0x7fffffff;
    if (lane < tot64) {
      int s = (lane >= o1) + (lane >= o2) + (lane >= o3);
      int src = lane - (s == 0 ? 0 : (s == 1 ? o1 : (s == 2 ? o2 : o3)));
      d2 = d2p[s][src];
      idx = idxp[s][src];
    }
    for (int k = 2; k <= 64; k <<= 1) {
      for (int jj = k >> 1; jj > 0; jj >>= 1) {
        float od2 = __shfl_xor(d2, jj);
        int oidx = __shfl_xor(idx, jj);
        bool up = ((lane & k) == 0);
        bool lower = ((lane & jj) == 0);
        bool takeMin = (lower == up);
        bool oLess = (od2 < d2) || (od2 == d2 && oidx < idx);
        bool take = takeMin ? oLess : !oLess;
        if (take) { d2 = od2; idx = oidx; }
      }
    }
    out_idx[q * KCAP + lane] = (lane < tot64) ? (float)idx : -1.0f;
    out_dist[q * KCAP + lane] = (lane < tot64) ? d2 : 0.0f;
    if (lane == 0) qcounts[q] = tot64;
  }
  __syncthreads();

  // Last-block ticket: the final block to arrive performs the scan.
  if (threadIdx.x == 0) {
    __threadfence();  // release our qcounts/out writes device-wide
    unsigned int t = atomicAdd((unsigned int*)done, 1u);
    amLastS = (t == (unsigned int)(gridDim.x - 1)) ? 1 : 0;
  }
  __syncthreads();
  if (amLastS) {
    __threadfence();  // acquire all blocks' qcounts
    const int t = threadIdx.x;
    const int base = t * 32;
    int s = 0;
#pragma unroll 4
    for (int j = 0; j < 32; ++j) {
      int i = base + j;
      s += (i < M) ? qcounts[i] : 0;
    }
    int pre = s;
    for (int off = 1; off < 64; off <<= 1) {
      int v = __shfl_up(pre, off);
      if (lane >= off) pre += v;
    }
    if (lane == 63) wsum[wv] = pre;
    __syncthreads();
    int woff = 0;
    for (int w = 0; w < wv; ++w) woff += wsum[w];
    int run = woff + pre - s;
    if (t == 0) out_rs[0] = 0.0f;
#pragma unroll 4
    for (int j = 0; j < 32; ++j) {
      int i = base + j;
      if (i < M) {
        run += qcounts[i];
        out_rs[1 + i] = (float)run;
      }
    }
  }
}

extern "C" void kernel_launch(void* const* d_in, const int* in_sizes, int n_in,
                              void* d_out, int out_size, void* d_ws, size_t ws_size,
                              hipStream_t stream) {
  const float* points = (const float*)d_in[0];
  const float* queries = (const float*)d_in[1];
  const float* radius = (const float*)d_in[2];
  const int N = in_sizes[0] / 3;  // 16384
  const int M = in_sizes[1] / 3;  // 8192

  float* out = (float*)d_out;
  float* out_idx = out;                    // [M, 64]
  float* out_rs = out + (size_t)M * KCAP;  // [M+1]
  float* out_dist = out_rs + (M + 1);      // [M, 64]

  // Workspace layout (float4 first for 16B alignment). ~18 MB total.
  float4* sortedPts = (float4*)d_ws;                      // GMAX*N
  int* sortedIdx = (int*)(sortedPts + (size_t)GMAX * N);  // GMAX*N
  int* rowStart = sortedIdx + (size_t)GMAX * N;           // GMAX*GMAX
  int* rowEnd = rowStart + GMAX * GMAX;                   // GMAX*GMAX
  int* qcounts = rowEnd + GMAX * GMAX;                    // M
  int* done = qcounts + M;                                // 1

  build_kernel<<<GMAX, 1024, 0, stream>>>(points, radius, sortedPts, sortedIdx,
                                          rowStart, rowEnd, done, N);
  query_kernel<<<M, 256, 0, stream>>>(queries, radius, sortedPts, sortedIdx,
                                      rowStart, rowEnd, out_idx, out_dist,
                                      out_rs, qcounts, done, N, M);
}

// Round 14
// 58.402 us; speedup vs baseline: 3.6342x; 3.6342x over previous
//
#include <hip/hip_runtime.h>
#include <math.h>

// Match numpy/XLA fp32 semantics: no compiler-introduced FMA contraction.
#pragma clang fp contract(off)

#define KCAP 64       // output neighbor cap (reference K)
#define GMAX 54       // max grid resolution per dim
#define XMIN -8.0f
#define SPAN 16.0f

// Same grid derivation as the passing round-5/11/12 kernels. cell >= 2r
// ensures any true neighbor is in the +-1 bin neighborhood under fp rounding.
__device__ __forceinline__ void grid_params(const float* __restrict__ radius_p,
                                            float* rr, float* cell, int* G) {
  float r = radius_p[0];
  *rr = r * r;
  float c = fmaxf(2.0f * r, SPAN / (float)GMAX);
  int g = (int)ceilf(SPAN / c);
  *G = g < 1 ? 1 : (g > GMAX ? GMAX : g);
  *cell = c;
}

__device__ __forceinline__ int bin1(float v, float cell, int G) {
  int b = (int)floorf((v - XMIN) / cell);
  return b < 0 ? 0 : (b > G - 1 ? G - 1 : b);
}

// Dispatch 1: 2D (y,z) counting sort, one block per z-row, fixed per-row
// capacity N (region base z*N). 4 sub-histograms (wave&3) cut LDS-atomic
// same-address chains 4x; pass A and B use the same thread->point mapping so
// per-slot capacities are exact. Within-cell order arbitrary (output sorted).
__global__ __launch_bounds__(1024) void build_kernel(
    const float* __restrict__ pts, const float* __restrict__ radius_p,
    float4* __restrict__ sortedPts, int* __restrict__ sortedIdx,
    int* __restrict__ rowStart, int* __restrict__ rowEnd, int N) {
  __shared__ int cnt[4][GMAX];
  __shared__ int cur[4][GMAX];
  float rr, cell; int G;
  grid_params(radius_p, &rr, &cell, &G);
  const int z = blockIdx.x;
  if (z >= G) return;
  const int sh = (threadIdx.x >> 6) & 3;  // sub-histogram id

  for (int i = threadIdx.x; i < 4 * GMAX; i += 1024) (&cnt[0][0])[i] = 0;
  __syncthreads();

  // Pass A: count this z-row's points per (sub-histogram, y-bin).
  for (int i = threadIdx.x; i < N; i += 1024) {
    float yv = pts[3 * i + 1], zv = pts[3 * i + 2];
    if (bin1(zv, cell, G) == z) atomicAdd(&cnt[sh][bin1(yv, cell, G)], 1);
  }
  __syncthreads();

  // Wave 0: scan <=54 y-bins; publish row ranges + per-sub-histogram cursors.
  if (threadIdx.x < 64) {
    int lane = threadIdx.x;
    int c0 = 0, c1 = 0, c2 = 0, c3 = 0, c = 0;
    if (lane < G) {
      c0 = cnt[0][lane]; c1 = cnt[1][lane];
      c2 = cnt[2][lane]; c3 = cnt[3][lane];
      c = c0 + c1 + c2 + c3;
    }
    int pre = c;
    for (int off = 1; off < 64; off <<= 1) {
      int v = __shfl_up(pre, off);
      if (lane >= off) pre += v;
    }
    if (lane < G) {
      int s0 = pre - c;  // exclusive prefix within this z-row
      rowStart[z * G + lane] = z * N + s0;
      rowEnd[z * G + lane] = z * N + pre;
      cur[0][lane] = s0;
      cur[1][lane] = s0 + c0;
      cur[2][lane] = s0 + c0 + c1;
      cur[3][lane] = s0 + c0 + c1 + c2;
    }
  }
  __syncthreads();

  // Pass B: scatter into cell-ordered storage as (x,y,z,p2).
  for (int i = threadIdx.x; i < N; i += 1024) {
    float xv = pts[3 * i], yv = pts[3 * i + 1], zv = pts[3 * i + 2];
    if (bin1(zv, cell, G) == z) {
      int pos = atomicAdd(&cur[sh][bin1(yv, cell, G)], 1);
      float p2 = (xv * xv + yv * yv) + zv * zv;  // numpy sum order, no fma
      sortedPts[z * N + pos] = make_float4(xv, yv, zv, p2);
      sortedIdx[z * N + pos] = i;
    }
  }
}

// Dispatch 2: one wave per query (4 queries / 256-thread block). 3 contiguous
// candidate ranges; depth-1 software-pipeline prefetch overlaps the next
// chunk's L2 load with the current chunk's ballot-compaction. 64-lane bitonic
// sort by (d2, idx) = jax.lax.top_k tie-break. No fences, no ticket.
__global__ __launch_bounds__(256) void query_kernel(
    const float* __restrict__ queries, const float* __restrict__ radius_p,
    const float4* __restrict__ sortedPts, const int* __restrict__ sortedIdx,
    const int* __restrict__ rowStart, const int* __restrict__ rowEnd,
    float* __restrict__ out_idx, float* __restrict__ out_dist,
    int* __restrict__ qcounts, int N, int M) {
  __shared__ float d2buf[4][KCAP];
  __shared__ int idxbuf[4][KCAP];
  const int lane = threadIdx.x & 63;
  const int wv = threadIdx.x >> 6;
  const int q = blockIdx.x * 4 + wv;
  if (q >= M) return;
  float rr, cell; int G;
  grid_params(radius_p, &rr, &cell, &G);

  float qx = queries[3 * q], qy = queries[3 * q + 1], qz = queries[3 * q + 2];
  float q2 = (qx * qx + qy * qy) + qz * qz;  // numpy sum order, no fma
  int cy = bin1(qy, cell, G), cz = bin1(qz, cell, G);
  int ylo = max(cy - 1, 0), yhi = min(cy + 1, G - 1);
  int rs_[3], re_[3];
  int nr = 0;
  for (int dz = -1; dz <= 1; ++dz) {
    int zz = cz + dz;
    if (zz < 0 || zz >= G) continue;
    rs_[nr] = rowStart[zz * G + ylo];
    re_[nr] = rowEnd[zz * G + yhi];
    ++nr;
  }

  const float4 PAD = make_float4(0.f, 0.f, 0.f, INFINITY);
  int cnt = 0;
  for (int t = 0; t < nr; ++t) {
    const int s = rs_[t], e = re_[t];
    int i0 = s + lane;
    float4 pcur = (i0 < e) ? sortedPts[i0] : PAD;  // first chunk
    for (int b = s; b < e; b += 64) {
      int inx = b + 64 + lane;
      float4 pnext = (inx < e) ? sortedPts[inx] : PAD;  // prefetch chunk t+1
      int i = b + lane;
      // Bit-identical per-pair arithmetic (all passing rounds):
      float dot = fmaf(pcur.z, qz, fmaf(pcur.y, qy, pcur.x * qx));
      float sdd = q2 + pcur.w;
      float d2 = fmaf(dot, -2.0f, sdd);   // == sdd - 2*dot exactly
      bool hit = (i < e) && (d2 <= rr);   // unclamped == clamped membership
      unsigned long long mask = __ballot(hit);
      int pos = cnt + __popcll(mask & ((1ull << lane) - 1ull));
      if (hit && pos < KCAP) {
        d2buf[wv][pos] = fmaxf(d2, 0.0f);  // clamp on store
        idxbuf[wv][pos] = sortedIdx[i];
      }
      cnt += __popcll(mask);
      pcur = pnext;
    }
  }

  int c64 = cnt < KCAP ? cnt : KCAP;
  float d2 = (lane < c64) ? d2buf[wv][lane] : INFINITY;
  int idx = (lane < c64) ? idxbuf[wv][lane] : 0x7fffffff;
  for (int k = 2; k <= 64; k <<= 1) {
    for (int jj = k >> 1; jj > 0; jj >>= 1) {
      float od2 = __shfl_xor(d2, jj);
      int oidx = __shfl_xor(idx, jj);
      bool up = ((lane & k) == 0);
      bool lower = ((lane & jj) == 0);
      bool takeMin = (lower == up);
      bool oLess = (od2 < d2) || (od2 == d2 && oidx < idx);
      bool take = takeMin ? oLess : !oLess;
      if (take) { d2 = od2; idx = oidx; }
    }
  }
  out_idx[q * KCAP + lane] = (lane < c64) ? (float)idx : -1.0f;
  out_dist[q * KCAP + lane] = (lane < c64) ? d2 : 0.0f;
  if (lane == 0) qcounts[q] = c64;
}

// Dispatch 3: row-splits scan (1 block; 256 threads x 32 counts each).
__global__ __launch_bounds__(256) void rs_scan_kernel(
    const int* __restrict__ counts, float* __restrict__ rs, int M) {
  __shared__ int wsum[4];
  const int tid = threadIdx.x;
  const int lane = tid & 63;
  const int wave = tid >> 6;
  const int base = tid * 32;
  int s = 0;
#pragma unroll 4
  for (int j = 0; j < 32; ++j) {
    int i = base + j;
    int c = (i < M) ? counts[i] : 0;
    s += (c < KCAP ? c : KCAP);
  }
  int pre = s;
  for (int off = 1; off < 64; off <<= 1) {
    int v = __shfl_up(pre, off);
    if (lane >= off) pre += v;
  }
  if (lane == 63) wsum[wave] = pre;
  __syncthreads();
  int woff = 0;
  for (int w = 0; w < wave; ++w) woff += wsum[w];
  int run = woff + pre - s;
  if (tid == 0) rs[0] = 0.0f;
#pragma unroll 4
  for (int j = 0; j < 32; ++j) {
    int i = base + j;
    if (i < M) {
      int c = counts[i];
      run += (c < KCAP ? c : KCAP);
      rs[1 + i] = (float)run;
    }
  }
}

extern "C" void kernel_launch(void* const* d_in, const int* in_sizes, int n_in,
                              void* d_out, int out_size, void* d_ws, size_t ws_size,
                              hipStream_t stream) {
  const float* points = (const float*)d_in[0];
  const float* queries = (const float*)d_in[1];
  const float* radius = (const float*)d_in[2];
  const int N = in_sizes[0] / 3;  // 16384
  const int M = in_sizes[1] / 3;  // 8192

  float* out = (float*)d_out;
  float* out_idx = out;                    // [M, 64]
  float* out_rs = out + (size_t)M * KCAP;  // [M+1]
  float* out_dist = out_rs + (M + 1);      // [M, 64]

  // Workspace layout (float4 first for 16B alignment). ~18 MB total.
  float4* sortedPts = (float4*)d_ws;                      // GMAX*N
  int* sortedIdx = (int*)(sortedPts + (size_t)GMAX * N);  // GMAX*N
  int* rowStart = sortedIdx + (size_t)GMAX * N;           // GMAX*GMAX
  int* rowEnd = rowStart + GMAX * GMAX;                   // GMAX*GMAX
  int* qcounts = rowEnd + GMAX * GMAX;                    // M

  build_kernel<<<GMAX, 1024, 0, stream>>>(points, radius, sortedPts, sortedIdx,
                                          rowStart, rowEnd, N);
  query_kernel<<<(M + 3) / 4, 256, 0, stream>>>(queries, radius, sortedPts,
                                                sortedIdx, rowStart, rowEnd,
                                                out_idx, out_dist, qcounts, N, M);
  rs_scan_kernel<<<1, 256, 0, stream>>>(qcounts, out_rs, M);
}